// Round 13
// baseline (76.310 us; speedup 1.0000x reference)
//
#include <hip/hip_runtime.h>
#include <hip/hip_bf16.h>

#define BB 4
#define SS 1024
#define NSD (BB*SS*64)

typedef __attribute__((ext_vector_type(4))) float f32x4;
typedef __attribute__((ext_vector_type(4))) unsigned int u32x4;
typedef __attribute__((ext_vector_type(8))) short bf16x8;

__device__ __forceinline__ float fast_exp2(float x) { return __builtin_amdgcn_exp2f(x); }
__device__ __forceinline__ float fast_rcp(float x)  { return __builtin_amdgcn_rcpf(x); }

__device__ __forceinline__ unsigned short f2bf(float f) {
    unsigned int u = __builtin_bit_cast(unsigned int, f);
    u += 0x7fffu + ((u >> 16) & 1u);
    return (unsigned short)(u >> 16);
}
__device__ __forceinline__ float bf2f(unsigned short u) {
    unsigned int v = (unsigned int)u << 16;
    return __builtin_bit_cast(float, v);
}

// sum of 4 sigmoids 1/(1+eq_d*ek_d) with one reciprocal
__device__ __forceinline__ float sig4(const f32x4 eq, const f32x4 ek) {
    float A = __builtin_fmaf(eq[0], ek[0], 1.0f);
    float B = __builtin_fmaf(eq[1], ek[1], 1.0f);
    float C = __builtin_fmaf(eq[2], ek[2], 1.0f);
    float D = __builtin_fmaf(eq[3], ek[3], 1.0f);
    float AB = A*B, CD = C*D;
    float num = __builtin_fmaf(A+B, CD, (C+D)*AB);
    return num * fast_rcp(AB*CD);
}

// bf16x8 -> two f32x4 (evens, odds). Order irrelevant (d-sum), alignment kept.
__device__ __forceinline__ void unpack8(bf16x8 v, f32x4& e, f32x4& o) {
    u32x4 u = __builtin_bit_cast(u32x4, v);
    #pragma unroll
    for (int i = 0; i < 4; ++i) {
        e[i] = __builtin_bit_cast(float, u[i] << 16);
        o[i] = __builtin_bit_cast(float, u[i] & 0xFFFF0000u);
    }
}

// ---------------------------------------------------------------------------
// K1: projections + hi/lo bf16 splits + exfb = bf16(exp(2x)).
// ---------------------------------------------------------------------------
__global__ __launch_bounds__(256) void k_proj(
    const float* __restrict__ x, const float* __restrict__ Wq,
    const float* __restrict__ Wk, const float* __restrict__ bkv,
    const float* __restrict__ Wv,
    unsigned short* __restrict__ qh, unsigned short* __restrict__ ql,
    unsigned short* __restrict__ kh, unsigned short* __restrict__ kl,
    unsigned short* __restrict__ xh, unsigned short* __restrict__ xlo,
    unsigned short* __restrict__ exfb,
    unsigned short* __restrict__ xT, unsigned short* __restrict__ vT)
{
    __shared__ float xsh[4*68];
    const int t = threadIdx.x;
    const int r = t & 3, cc = t >> 2;
    const int row0 = blockIdx.x * 4;
    if (t < 64) {
        const int rr = t >> 4, seg = (t & 15) * 4;
        *(f32x4*)(xsh + rr*68 + seg) =
            *(const f32x4*)(x + (size_t)(row0 + rr)*64 + seg);
    }
    __syncthreads();

    const float* wqp = Wq + cc*64;
    const float* wkp = Wk + cc*64;
    const float* wvp = Wv + cc*64;
    float aq = 0.f, ak = 0.f, av = 0.f;
    #pragma unroll 4
    for (int e0 = 0; e0 < 64; e0 += 4) {
        f32x4 xv = *(const f32x4*)(xsh + r*68 + e0);
        f32x4 q4 = *(const f32x4*)(wqp + e0);
        f32x4 k4 = *(const f32x4*)(wkp + e0);
        f32x4 v4 = *(const f32x4*)(wvp + e0);
        #pragma unroll
        for (int u = 0; u < 4; ++u) {
            aq = __builtin_fmaf(xv[u], q4[u], aq);
            ak = __builtin_fmaf(xv[u], k4[u], ak);
            av = __builtin_fmaf(xv[u], v4[u], av);
        }
    }
    const int row = row0 + r;
    const int b = row >> 10, srow = row & 1023;
    const float C2 = 2.8853900817779268f;   // 2*log2(e)
    ak += bkv[cc];
    const size_t idx = (size_t)row*64 + cc;
    unsigned short h;
    h = f2bf(aq); qh[idx] = h; ql[idx] = f2bf(aq - bf2f(h));
    h = f2bf(ak); kh[idx] = h; kl[idx] = f2bf(ak - bf2f(h));
    const float xv_ = xsh[r*68 + cc];
    h = f2bf(xv_); xh[idx] = h; xlo[idx] = f2bf(xv_ - bf2f(h));
    exfb[idx] = f2bf(fast_exp2(C2 * xv_));
    xT[((size_t)b*64 + cc)*1024 + srow] = h;
    vT[((size_t)b*64 + cc)*1024 + srow] = f2bf(av);
}

// ---------------------------------------------------------------------------
// K2: merged fused kernel, 1600 blocks x 256, LDS 30 KB (5 blocks/CU by LDS).
//  bx < 576 : branch 3. Block=(b, qt32 desc, cg); wave wv -> chunk c=cg*4+wv
//    (32q x 32k). eq bf16 [32][64] shared; ek bf16 [32][64] per-wave; both
//    XOR-swizzled by octet (o^(r&7)); inner loop: per d-octet 8 ds_read_b128
//    + 8 unpack + 32 sig4 (DS:VALU ~0.42). P per-wave [32][40] -> MFMA vs
//    xT. Slot-per-chunk (4+c, 36 slots) -> no in-block reduce, 1 barrier.
//  bx >= 576 : branches 1,2 (split-bf16 MFMA scores; verified r6-r12).
// ---------------------------------------------------------------------------
__global__ __launch_bounds__(256) void k_fused(
    const unsigned short* __restrict__ xh, const unsigned short* __restrict__ xlo,
    const unsigned short* __restrict__ qh, const unsigned short* __restrict__ ql,
    const unsigned short* __restrict__ kh, const unsigned short* __restrict__ kl,
    const unsigned short* __restrict__ exfb,
    const unsigned short* __restrict__ xT, const unsigned short* __restrict__ vT,
    const float* __restrict__ attn_scale,
    float* __restrict__ po, float* __restrict__ lb)
{
    // u16 carve: eq[2048] | ek 4x2048 | P 4x1280  => 15360 u16 = 30 KB
    __shared__ __align__(16) unsigned short smem[15360];
    const int t = threadIdx.x;
    const int bx = blockIdx.x;
    const int lane = t & 63, wv = t >> 6;
    const int l15 = lane & 15, g = lane >> 4;
    const float LOG2E = 1.4426950408889634f;

    if (bx < 576) {
        // ================= branch 3 =================
        const int b = bx / 144;
        int rr = bx % 144;
        int qt32 = 31;
        while (rr >= ((qt32 >> 2) + 1)) { rr -= (qt32 >> 2) + 1; --qt32; }
        const int cg = rr;
        const int q0 = qt32 * 32;
        const int c = cg*4 + wv;
        const bool active = (c <= qt32);
        const int kc = c * 32;
        const int l7 = lane & 7, lk3 = lane >> 3;

        unsigned short* eqb = smem;                    // [32][64] swz, shared
        unsigned short* ekw = smem + 2048 + wv*2048;   // [32][64] swz, per-wave
        unsigned short* Plw = smem + 10240 + wv*1280;  // [32][40]

        {   // stage eq: 256 octets (16B each) by 256 threads
            const int r0 = t >> 3, o0 = t & 7;
            *(bf16x8*)(eqb + r0*64 + ((o0 ^ (r0 & 7)) << 3)) =
                *(const bf16x8*)(exfb + ((size_t)b*SS + q0 + r0)*64 + o0*8);
        }
        if (active) {   // stage own ek: 4 octets per lane
            #pragma unroll
            for (int ii = 0; ii < 4; ++ii) {
                const int jdx = lane + 64*ii;
                const int r0 = jdx >> 3, o0 = jdx & 7;
                *(bf16x8*)(ekw + r0*64 + ((o0 ^ (r0 & 7)) << 3)) =
                    *(const bf16x8*)(exfb + ((size_t)b*SS + kc + r0)*64 + o0*8);
            }
        }
        __syncthreads();

        if (active) {
            float ar[4][4] = {};
            #pragma unroll
            for (int m8 = 0; m8 < 8; ++m8) {
                const int oq = (m8 ^ l7) << 3;
                const int ok = (m8 ^ lk3) << 3;
                f32x4 eqe[4], eqo[4], eke[4], eko[4];
                #pragma unroll
                for (int i = 0; i < 4; ++i) {
                    bf16x8 v = *(const bf16x8*)(eqb + (l7 + 8*i)*64 + oq);
                    unpack8(v, eqe[i], eqo[i]);
                }
                #pragma unroll
                for (int j = 0; j < 4; ++j) {
                    bf16x8 v = *(const bf16x8*)(ekw + (lk3 + 8*j)*64 + ok);
                    unpack8(v, eke[j], eko[j]);
                }
                #pragma unroll
                for (int i = 0; i < 4; ++i)
                    #pragma unroll
                    for (int j = 0; j < 4; ++j)
                        ar[i][j] += sig4(eqe[i], eke[j]) + sig4(eqo[i], eko[j]);
            }
            // p = e^{s3-32}, s3 = 64-2ar; causal mask; P->LDS; row sums
            float lrow[4] = {0.f,0.f,0.f,0.f};
            #pragma unroll
            for (int i = 0; i < 4; ++i) {
                const int q = q0 + l7 + 8*i;
                #pragma unroll
                for (int j = 0; j < 4; ++j) {
                    const int k = kc + lk3 + 8*j;
                    float e = (k <= q)
                        ? fast_exp2(__builtin_fmaf(ar[i][j], -2.8853900817779268f,
                                                   46.166241308446475f))
                        : 0.f;
                    lrow[i] += e;
                    Plw[(l7 + 8*i)*40 + lk3 + 8*j] = f2bf(e);
                }
            }
            #pragma unroll
            for (int i = 0; i < 4; ++i) {
                lrow[i] += __shfl_xor(lrow[i], 8, 64);
                lrow[i] += __shfl_xor(lrow[i], 16, 64);
                lrow[i] += __shfl_xor(lrow[i], 32, 64);
            }
            // PV: 2 q-halves x 4 d-blocks, B-frags direct from xT
            f32x4 acc[2][4];
            #pragma unroll
            for (int a_ = 0; a_ < 2; ++a_)
                #pragma unroll
                for (int d_ = 0; d_ < 4; ++d_)
                    acc[a_][d_] = (f32x4){0.f,0.f,0.f,0.f};
            const unsigned short* vb = xT + (size_t)b*64*1024;
            #pragma unroll
            for (int qh2 = 0; qh2 < 2; ++qh2) {
                bf16x8 af = *(const bf16x8*)(Plw + (qh2*16 + l15)*40 + g*8);
                #pragma unroll
                for (int db = 0; db < 4; ++db) {
                    bf16x8 bf_ = *(const bf16x8*)(vb + (size_t)(db*16 + l15)*1024 + kc + g*8);
                    acc[qh2][db] = __builtin_amdgcn_mfma_f32_16x16x32_bf16(af, bf_, acc[qh2][db], 0, 0, 0);
                }
            }
            // per-wave epilogue: slot 4+c (no cross-wave reduce, no barrier)
            const size_t slot = 4 + c;
            if (lane < 8) {
                #pragma unroll
                for (int i = 0; i < 4; ++i)
                    lb[slot*(size_t)(BB*SS) + (size_t)b*SS + q0 + l7 + 8*i] = lrow[i];
            }
            float* pob = po + slot*(size_t)NSD + ((size_t)b*SS + q0)*64;
            #pragma unroll
            for (int qh2 = 0; qh2 < 2; ++qh2)
                #pragma unroll
                for (int i = 0; i < 4; ++i) {
                    const int row = qh2*16 + g*4 + i;
                    #pragma unroll
                    for (int db = 0; db < 4; ++db)
                        pob[(size_t)row*64 + db*16 + l15] = acc[qh2][db][i];
                }
        }
    } else {
        // ================= branches 1,2 (verified path, smem aliased) =======
        unsigned short* Pl = smem;                     // [16][72] u16
        float* lpart = (float*)(smem + 2048);          // [4][16] f32
        const int y = bx - 576;
        const int split = y & 1, b = (y >> 1) & 3;
        const int qt = 63 - ((y >> 3) & 63);
        const int br = (y >> 9) & 1;
        const int q0 = qt * 16;
        const int nc = (qt >> 2) + 1;

        const unsigned short* Ah_p = (br ? qh : xh) + ((size_t)b*SS + q0)*64;
        const unsigned short* Al_p = (br ? ql : xlo) + ((size_t)b*SS + q0)*64;
        const unsigned short* Bh_p = (br ? kh : xh) + (size_t)b*SS*64;
        const unsigned short* Bl_p = (br ? kl : xlo) + (size_t)b*SS*64;
        const unsigned short* Vb   = (br ? vT : xT) + (size_t)b*64*1024;

        const int ko = g * 8;
        bf16x8 Ah0 = *(const bf16x8*)(Ah_p + (size_t)l15*64 + ko);
        bf16x8 Ah1 = *(const bf16x8*)(Ah_p + (size_t)l15*64 + 32 + ko);
        bf16x8 Al0 = *(const bf16x8*)(Al_p + (size_t)l15*64 + ko);
        bf16x8 Al1 = *(const bf16x8*)(Al_p + (size_t)l15*64 + 32 + ko);

        const float pscale = br ? (0.125f * attn_scale[0] * LOG2E) : LOG2E;
        const float pshift = br ? 0.f : (-64.f * LOG2E);

        f32x4 lacc = {0,0,0,0};
        f32x4 oacc = {0,0,0,0};

        for (int cc2 = split; cc2 < nc; cc2 += 2) {
            const int kc = cc2 * 64;
            const int krow = kc + wv*16 + l15;
            bf16x8 Bh0 = *(const bf16x8*)(Bh_p + (size_t)krow*64 + ko);
            bf16x8 Bh1 = *(const bf16x8*)(Bh_p + (size_t)krow*64 + 32 + ko);
            bf16x8 Bl0 = *(const bf16x8*)(Bl_p + (size_t)krow*64 + ko);
            bf16x8 Bl1 = *(const bf16x8*)(Bl_p + (size_t)krow*64 + 32 + ko);
            f32x4 s = {0,0,0,0};
            s = __builtin_amdgcn_mfma_f32_16x16x32_bf16(Ah0, Bh0, s, 0, 0, 0);
            s = __builtin_amdgcn_mfma_f32_16x16x32_bf16(Ah1, Bh1, s, 0, 0, 0);
            s = __builtin_amdgcn_mfma_f32_16x16x32_bf16(Ah0, Bl0, s, 0, 0, 0);
            s = __builtin_amdgcn_mfma_f32_16x16x32_bf16(Ah1, Bl1, s, 0, 0, 0);
            s = __builtin_amdgcn_mfma_f32_16x16x32_bf16(Al0, Bh0, s, 0, 0, 0);
            s = __builtin_amdgcn_mfma_f32_16x16x32_bf16(Al1, Bh1, s, 0, 0, 0);
            const int kg = kc + wv*16 + l15;
            #pragma unroll
            for (int i = 0; i < 4; ++i) {
                const int q = q0 + g*4 + i;
                float e = (kg <= q) ? fast_exp2(__builtin_fmaf(s[i], pscale, pshift)) : 0.f;
                lacc[i] += e;
                Pl[(g*4+i)*72 + wv*16 + l15] = f2bf(e);
            }
            __syncthreads();
            #pragma unroll
            for (int ks = 0; ks < 2; ++ks) {
                bf16x8 af = *(const bf16x8*)(Pl + l15*72 + ks*32 + g*8);
                bf16x8 bf_ = *(const bf16x8*)(Vb + (size_t)(wv*16 + l15)*1024 + kc + ks*32 + g*8);
                oacc = __builtin_amdgcn_mfma_f32_16x16x32_bf16(af, bf_, oacc, 0, 0, 0);
            }
            __syncthreads();
        }
        #pragma unroll
        for (int off = 8; off >= 1; off >>= 1) {
            lacc[0] += __shfl_xor(lacc[0], off, 64);
            lacc[1] += __shfl_xor(lacc[1], off, 64);
            lacc[2] += __shfl_xor(lacc[2], off, 64);
            lacc[3] += __shfl_xor(lacc[3], off, 64);
        }
        if (l15 == 0) {
            #pragma unroll
            for (int i = 0; i < 4; ++i) lpart[wv*16 + g*4 + i] = lacc[i];
        }
        __syncthreads();
        const size_t slot = (size_t)(br*2 + split);
        if (t < 16) {
            float l = lpart[t] + lpart[16 + t] + lpart[32 + t] + lpart[48 + t];
            lb[slot*((size_t)BB*SS) + (size_t)b*SS + q0 + t] = l;
        }
        float* pob = po + slot*((size_t)NSD) + ((size_t)b*SS + q0)*64;
        #pragma unroll
        for (int i = 0; i < 4; ++i)
            pob[(size_t)(g*4 + i)*64 + wv*16 + l15] = oacc[i];
    }
}

// ---------------------------------------------------------------------------
// K3: out = w0*(p0+p1)/(l0+l1) + w1*(p2+p3)/(l2+l3) + w2*(br3 slots s<=band)
// band = (row_in_batch >> 5); br3 slots are 4+s, s in [0, band].
// ---------------------------------------------------------------------------
__global__ __launch_bounds__(256) void k_comb(
    const float* __restrict__ po, const float* __restrict__ lb,
    const float* __restrict__ attn_w, float* __restrict__ out)
{
    const int v = blockIdx.x*256 + threadIdx.x;      // f32x4 index over [B,S,D]
    const int qg = v >> 4;                           // global row b*S+q
    const int band = (qg & 1023) >> 5;
    const float aw0 = attn_w[0], aw1 = attn_w[1], aw2 = attn_w[2];
    const float iws = fast_rcp(aw0 + aw1 + aw2);
    const f32x4* p = (const f32x4*)po;
    const int NQ = BB*SS;

    f32x4 s01 = p[(size_t)0*65536 + v] + p[(size_t)1*65536 + v];
    f32x4 s23 = p[(size_t)2*65536 + v] + p[(size_t)3*65536 + v];
    f32x4 s3s = {0,0,0,0};
    float l3 = 0.f;
    for (int s = 0; s <= band; ++s) {
        s3s += p[(size_t)(4+s)*65536 + v];
        l3 += lb[(4+s)*NQ + qg];
    }
    const float f0 = aw0 * iws * fast_rcp(lb[0*NQ + qg] + lb[1*NQ + qg]);
    const float f1 = aw1 * iws * fast_rcp(lb[2*NQ + qg] + lb[3*NQ + qg]);
    const float f2 = aw2 * iws * fast_rcp(l3);
    f32x4 o;
    #pragma unroll
    for (int u = 0; u < 4; ++u)
        o[u] = __builtin_fmaf(s01[u], f0,
               __builtin_fmaf(s23[u], f1, s3s[u]*f2));
    ((f32x4*)out)[v] = o;
}

extern "C" void kernel_launch(void* const* d_in, const int* in_sizes, int n_in,
                              void* d_out, int out_size, void* d_ws, size_t ws_size,
                              hipStream_t stream) {
    (void)in_sizes; (void)n_in; (void)out_size; (void)ws_size;
    const float* x          = (const float*)d_in[0];
    const float* Wq         = (const float*)d_in[1];
    const float* Wk         = (const float*)d_in[2];
    const float* bk         = (const float*)d_in[3];
    const float* Wv         = (const float*)d_in[4];
    const float* attn_w     = (const float*)d_in[5];
    const float* attn_scale = (const float*)d_in[6];
    float* out              = (float*)d_out;

    // workspace carve-up (~43 MB; ws is ~268 MB)
    unsigned short* exfb = (unsigned short*)d_ws;         // bf16 [B,S,64]
    unsigned short* qh  = exfb + NSD;                     // 6 bf16 [B,S,64]
    unsigned short* ql  = qh  + NSD;
    unsigned short* kh  = ql  + NSD;
    unsigned short* kl  = kh  + NSD;
    unsigned short* xh  = kl  + NSD;
    unsigned short* xlo = xh  + NSD;
    unsigned short* xT  = xlo + NSD;                      // bf16 [B,64,S]
    unsigned short* vT  = xT  + NSD;
    float* po = (float*)(vT + NSD);                       // [36][B,S,64] f32
    float* lb = po + (size_t)36*NSD;                      // [36][B*S]

    k_proj <<<1024, 256, 0, stream>>>(x, Wq, Wk, bk, Wv,
                                      qh, ql, kh, kl, xh, xlo, exfb, xT, vT);
    k_fused<<<1600, 256, 0, stream>>>(xh, xlo, qh, ql, kh, kl, exfb, xT, vT,
                                      attn_scale, po, lb);
    k_comb <<<256, 256, 0, stream>>>(po, lb, attn_w, out);
}

// Round 14
// 72.903 us; speedup vs baseline: 1.0467x; 1.0467x over previous
//
#include <hip/hip_runtime.h>
#include <hip/hip_bf16.h>

#define BB 4
#define SS 1024
#define NSD (BB*SS*64)

typedef __attribute__((ext_vector_type(4))) float f32x4;
typedef __attribute__((ext_vector_type(4))) unsigned int u32x4;
typedef __attribute__((ext_vector_type(8))) short bf16x8;

__device__ __forceinline__ float fast_exp2(float x) { return __builtin_amdgcn_exp2f(x); }
__device__ __forceinline__ float fast_rcp(float x)  { return __builtin_amdgcn_rcpf(x); }

__device__ __forceinline__ unsigned short f2bf(float f) {
    unsigned int u = __builtin_bit_cast(unsigned int, f);
    u += 0x7fffu + ((u >> 16) & 1u);
    return (unsigned short)(u >> 16);
}
__device__ __forceinline__ float bf2f(unsigned short u) {
    unsigned int v = (unsigned int)u << 16;
    return __builtin_bit_cast(float, v);
}

// sum of 4 sigmoids 1/(1+eq_d*ek_d) with one reciprocal
__device__ __forceinline__ float sig4(const f32x4 eq, const f32x4 ek) {
    float A = __builtin_fmaf(eq[0], ek[0], 1.0f);
    float B = __builtin_fmaf(eq[1], ek[1], 1.0f);
    float C = __builtin_fmaf(eq[2], ek[2], 1.0f);
    float D = __builtin_fmaf(eq[3], ek[3], 1.0f);
    float AB = A*B, CD = C*D;
    float num = __builtin_fmaf(A+B, CD, (C+D)*AB);
    return num * fast_rcp(AB*CD);
}

// ---------------------------------------------------------------------------
// K1: projections + hi/lo bf16 splits + exf f32 (r12 version, verified).
// ---------------------------------------------------------------------------
__global__ __launch_bounds__(256) void k_proj(
    const float* __restrict__ x, const float* __restrict__ Wq,
    const float* __restrict__ Wk, const float* __restrict__ bkv,
    const float* __restrict__ Wv,
    unsigned short* __restrict__ qh, unsigned short* __restrict__ ql,
    unsigned short* __restrict__ kh, unsigned short* __restrict__ kl,
    unsigned short* __restrict__ xh, unsigned short* __restrict__ xlo,
    float* __restrict__ exf,
    unsigned short* __restrict__ xT, unsigned short* __restrict__ vT)
{
    __shared__ float xsh[4*68];
    const int t = threadIdx.x;
    const int r = t & 3, cc = t >> 2;
    const int row0 = blockIdx.x * 4;
    if (t < 64) {
        const int rr = t >> 4, seg = (t & 15) * 4;
        *(f32x4*)(xsh + rr*68 + seg) =
            *(const f32x4*)(x + (size_t)(row0 + rr)*64 + seg);
    }
    __syncthreads();

    const float* wqp = Wq + cc*64;
    const float* wkp = Wk + cc*64;
    const float* wvp = Wv + cc*64;
    float aq = 0.f, ak = 0.f, av = 0.f;
    #pragma unroll 4
    for (int e0 = 0; e0 < 64; e0 += 4) {
        f32x4 xv = *(const f32x4*)(xsh + r*68 + e0);
        f32x4 q4 = *(const f32x4*)(wqp + e0);
        f32x4 k4 = *(const f32x4*)(wkp + e0);
        f32x4 v4 = *(const f32x4*)(wvp + e0);
        #pragma unroll
        for (int u = 0; u < 4; ++u) {
            aq = __builtin_fmaf(xv[u], q4[u], aq);
            ak = __builtin_fmaf(xv[u], k4[u], ak);
            av = __builtin_fmaf(xv[u], v4[u], av);
        }
    }
    const int row = row0 + r;
    const int b = row >> 10, srow = row & 1023;
    const float C2 = 2.8853900817779268f;   // 2*log2(e)
    ak += bkv[cc];
    const size_t idx = (size_t)row*64 + cc;
    unsigned short h;
    h = f2bf(aq); qh[idx] = h; ql[idx] = f2bf(aq - bf2f(h));
    h = f2bf(ak); kh[idx] = h; kl[idx] = f2bf(ak - bf2f(h));
    const float xv_ = xsh[r*68 + cc];
    h = f2bf(xv_); xh[idx] = h; xlo[idx] = f2bf(xv_ - bf2f(h));
    exf[idx] = fast_exp2(C2 * xv_);
    xT[((size_t)b*64 + cc)*1024 + srow] = h;
    vT[((size_t)b*64 + cc)*1024 + srow] = f2bf(av);
}

// ---------------------------------------------------------------------------
// K2: merged fused kernel, 1296 blocks x 256.
//  bx < 272 : branch 3, REGISTER-RESIDENT: 4 independent waves/block, each =
//    one uniform job (b, qt64, c) = 64q x 32k chunk. Lane = q-row q0+lane,
//    full eq (64 f32) in VGPRs; ek wave-uniform from exf, double-buffered in
//    regs (prefetch k+1 during k); NO LDS in score loop (P via 1 ds_write_b16
//    per k to wave-private [64][40]); per-lane lsum (no shuffles/barriers).
//    PV: 4x4 single MFMAs (C=0) -> po slot 4+c (36 slots).
//  bx >= 272 : branches 1,2 (split-bf16 MFMA scores; verified r6-r13).
// LDS 20KB; VGPR ~220 -> ~8 blocks/CU allowed; br3 = 1088 waves uniform.
// ---------------------------------------------------------------------------
__global__ __launch_bounds__(256) void k_fused(
    const unsigned short* __restrict__ xh, const unsigned short* __restrict__ xlo,
    const unsigned short* __restrict__ qh, const unsigned short* __restrict__ ql,
    const unsigned short* __restrict__ kh, const unsigned short* __restrict__ kl,
    const float* __restrict__ exf,
    const unsigned short* __restrict__ xT, const unsigned short* __restrict__ vT,
    const float* __restrict__ attn_scale,
    float* __restrict__ po, float* __restrict__ lb)
{
    __shared__ __align__(16) unsigned short smem[10240];   // 20 KB
    const int t = threadIdx.x;
    const int bx = blockIdx.x;
    const int lane = t & 63, wv = t >> 6;
    const int l15 = lane & 15, g = lane >> 4;
    const float LOG2E = 1.4426950408889634f;

    if (bx < 272) {
        // ================= branch 3: register-resident =================
        const int j = bx*4 + wv;             // 0..1087
        const int b = j >> 8 == 0 ? 0 : 0;   // placeholder (recomputed below)
        const int bb = j / 272;
        int rr = j - bb*272;
        int qt = 15;
        while (rr >= 2*(qt+1)) { rr -= 2*(qt+1); --qt; }
        const int c = rr;                    // 0 .. 2qt+1
        const int q0 = qt * 64;
        const int kc0 = c * 32;
        const int q = q0 + lane;
        (void)b;

        // eq: lane's q-row, 64 f32 in registers (coalescible 16x b128)
        f32x4 eq[16];
        {
            const float* eqp = exf + ((size_t)bb*SS + q0 + lane)*64;
            #pragma unroll
            for (int dq = 0; dq < 16; ++dq)
                eq[dq] = *(const f32x4*)(eqp + dq*4);
        }

        unsigned short* Plw = smem + wv*2560;      // [64][40] u16, wave-private
        const float* ekb = exf + ((size_t)bb*SS + kc0)*64;

        // prime ekA with k = kc0
        f32x4 ekA[16], ekB[16];
        #pragma unroll
        for (int dq = 0; dq < 16; ++dq)
            ekA[dq] = *(const f32x4*)(ekb + dq*4);

        float lsum = 0.f;
        const float EC = -2.8853900817779268f;     // -2*log2e
        const float ES = 46.166241308446475f;      // 32*log2e*... e^{s3-32}

        for (int kk = 0; kk < 32; kk += 2) {
            {   // phase A: prefetch kk+1 -> ekB, compute k = kc0+kk with ekA
                const float* nk = ekb + (size_t)(kk+1)*64;
                #pragma unroll
                for (int dq = 0; dq < 16; ++dq)
                    ekB[dq] = *(const f32x4*)(nk + dq*4);
                float s0=0.f, s1=0.f, s2=0.f, s3=0.f;
                #pragma unroll
                for (int dq = 0; dq < 16; dq += 4) {
                    s0 += sig4(eq[dq+0], ekA[dq+0]);
                    s1 += sig4(eq[dq+1], ekA[dq+1]);
                    s2 += sig4(eq[dq+2], ekA[dq+2]);
                    s3 += sig4(eq[dq+3], ekA[dq+3]);
                }
                const float ar = (s0+s1)+(s2+s3);
                float e = (kc0+kk <= q) ? fast_exp2(__builtin_fmaf(ar, EC, ES)) : 0.f;
                lsum += e;
                Plw[lane*40 + kk] = f2bf(e);
            }
            {   // phase B: prefetch kk+2 (wrapped) -> ekA, compute kc0+kk+1 with ekB
                const float* nk = ekb + (size_t)((kk+2) & 31)*64;
                #pragma unroll
                for (int dq = 0; dq < 16; ++dq)
                    ekA[dq] = *(const f32x4*)(nk + dq*4);
                float s0=0.f, s1=0.f, s2=0.f, s3=0.f;
                #pragma unroll
                for (int dq = 0; dq < 16; dq += 4) {
                    s0 += sig4(eq[dq+0], ekB[dq+0]);
                    s1 += sig4(eq[dq+1], ekB[dq+1]);
                    s2 += sig4(eq[dq+2], ekB[dq+2]);
                    s3 += sig4(eq[dq+3], ekB[dq+3]);
                }
                const float ar = (s0+s1)+(s2+s3);
                float e = (kc0+kk+1 <= q) ? fast_exp2(__builtin_fmaf(ar, EC, ES)) : 0.f;
                lsum += e;
                Plw[lane*40 + kk + 1] = f2bf(e);
            }
        }

        // PV: A-frags from wave-private P (r2-verified layout), B from xT
        const unsigned short* vb = xT + (size_t)bb*64*1024;
        bf16x8 bfr[4];
        #pragma unroll
        for (int db = 0; db < 4; ++db)
            bfr[db] = *(const bf16x8*)(vb + (size_t)(db*16 + l15)*1024 + kc0 + g*8);

        const size_t slot = 4 + c;
        float* pob = po + slot*(size_t)NSD + ((size_t)bb*SS + q0)*64;
        #pragma unroll
        for (int rt = 0; rt < 4; ++rt) {
            bf16x8 af = *(const bf16x8*)(Plw + (rt*16 + l15)*40 + g*8);
            #pragma unroll
            for (int db = 0; db < 4; ++db) {
                f32x4 acc = {0.f,0.f,0.f,0.f};
                acc = __builtin_amdgcn_mfma_f32_16x16x32_bf16(af, bfr[db], acc, 0, 0, 0);
                #pragma unroll
                for (int i = 0; i < 4; ++i)
                    pob[(size_t)(rt*16 + g*4 + i)*64 + db*16 + l15] = acc[i];
            }
        }
        lb[slot*(size_t)(BB*SS) + (size_t)bb*SS + q0 + lane] = lsum;
    } else {
        // ================= branches 1,2 (verified path, smem aliased) =======
        unsigned short* Pl = smem;                     // [16][72] u16
        float* lpart = (float*)(smem + 2048);          // [4][16] f32
        const int y = bx - 272;
        const int split = y & 1, b = (y >> 1) & 3;
        const int qt = 63 - ((y >> 3) & 63);
        const int br = (y >> 9) & 1;
        const int q0 = qt * 16;
        const int nc = (qt >> 2) + 1;

        const unsigned short* Ah_p = (br ? qh : xh) + ((size_t)b*SS + q0)*64;
        const unsigned short* Al_p = (br ? ql : xlo) + ((size_t)b*SS + q0)*64;
        const unsigned short* Bh_p = (br ? kh : xh) + (size_t)b*SS*64;
        const unsigned short* Bl_p = (br ? kl : xlo) + (size_t)b*SS*64;
        const unsigned short* Vb   = (br ? vT : xT) + (size_t)b*64*1024;

        const int ko = g * 8;
        bf16x8 Ah0 = *(const bf16x8*)(Ah_p + (size_t)l15*64 + ko);
        bf16x8 Ah1 = *(const bf16x8*)(Ah_p + (size_t)l15*64 + 32 + ko);
        bf16x8 Al0 = *(const bf16x8*)(Al_p + (size_t)l15*64 + ko);
        bf16x8 Al1 = *(const bf16x8*)(Al_p + (size_t)l15*64 + 32 + ko);

        const float pscale = br ? (0.125f * attn_scale[0] * LOG2E) : LOG2E;
        const float pshift = br ? 0.f : (-64.f * LOG2E);

        f32x4 lacc = {0,0,0,0};
        f32x4 oacc = {0,0,0,0};

        for (int cc2 = split; cc2 < nc; cc2 += 2) {
            const int kc = cc2 * 64;
            const int krow = kc + wv*16 + l15;
            bf16x8 Bh0 = *(const bf16x8*)(Bh_p + (size_t)krow*64 + ko);
            bf16x8 Bh1 = *(const bf16x8*)(Bh_p + (size_t)krow*64 + 32 + ko);
            bf16x8 Bl0 = *(const bf16x8*)(Bl_p + (size_t)krow*64 + ko);
            bf16x8 Bl1 = *(const bf16x8*)(Bl_p + (size_t)krow*64 + 32 + ko);
            f32x4 s = {0,0,0,0};
            s = __builtin_amdgcn_mfma_f32_16x16x32_bf16(Ah0, Bh0, s, 0, 0, 0);
            s = __builtin_amdgcn_mfma_f32_16x16x32_bf16(Ah1, Bh1, s, 0, 0, 0);
            s = __builtin_amdgcn_mfma_f32_16x16x32_bf16(Ah0, Bl0, s, 0, 0, 0);
            s = __builtin_amdgcn_mfma_f32_16x16x32_bf16(Ah1, Bl1, s, 0, 0, 0);
            s = __builtin_amdgcn_mfma_f32_16x16x32_bf16(Al0, Bh0, s, 0, 0, 0);
            s = __builtin_amdgcn_mfma_f32_16x16x32_bf16(Al1, Bh1, s, 0, 0, 0);
            const int kg = kc + wv*16 + l15;
            #pragma unroll
            for (int i = 0; i < 4; ++i) {
                const int qrow = q0 + g*4 + i;
                float e = (kg <= qrow) ? fast_exp2(__builtin_fmaf(s[i], pscale, pshift)) : 0.f;
                lacc[i] += e;
                Pl[(g*4+i)*72 + wv*16 + l15] = f2bf(e);
            }
            __syncthreads();
            #pragma unroll
            for (int ks = 0; ks < 2; ++ks) {
                bf16x8 af = *(const bf16x8*)(Pl + l15*72 + ks*32 + g*8);
                bf16x8 bf_ = *(const bf16x8*)(Vb + (size_t)(wv*16 + l15)*1024 + kc + ks*32 + g*8);
                oacc = __builtin_amdgcn_mfma_f32_16x16x32_bf16(af, bf_, oacc, 0, 0, 0);
            }
            __syncthreads();
        }
        #pragma unroll
        for (int off = 8; off >= 1; off >>= 1) {
            lacc[0] += __shfl_xor(lacc[0], off, 64);
            lacc[1] += __shfl_xor(lacc[1], off, 64);
            lacc[2] += __shfl_xor(lacc[2], off, 64);
            lacc[3] += __shfl_xor(lacc[3], off, 64);
        }
        if (l15 == 0) {
            #pragma unroll
            for (int i = 0; i < 4; ++i) lpart[wv*16 + g*4 + i] = lacc[i];
        }
        __syncthreads();
        const size_t slot = (size_t)(br*2 + split);
        if (t < 16) {
            float l = lpart[t] + lpart[16 + t] + lpart[32 + t] + lpart[48 + t];
            lb[slot*((size_t)BB*SS) + (size_t)b*SS + q0 + t] = l;
        }
        float* pob = po + slot*((size_t)NSD) + ((size_t)b*SS + q0)*64;
        #pragma unroll
        for (int i = 0; i < 4; ++i)
            pob[(size_t)(g*4 + i)*64 + wv*16 + l15] = oacc[i];
    }
}

// ---------------------------------------------------------------------------
// K3: out = w0*(p0+p1)/(l0+l1) + w1*(p2+p3)/(l2+l3) + w2*(br3 slots s < ns)
// ns per row = 2*((row_in_batch >> 6) + 1)  (32k chunks over causal range).
// ---------------------------------------------------------------------------
__global__ __launch_bounds__(256) void k_comb(
    const float* __restrict__ po, const float* __restrict__ lb,
    const float* __restrict__ attn_w, float* __restrict__ out)
{
    const int v = blockIdx.x*256 + threadIdx.x;      // f32x4 index over [B,S,D]
    const int qg = v >> 4;                           // global row b*S+q
    const int ns = 2*(((qg & 1023) >> 6) + 1);       // 2..32
    const float aw0 = attn_w[0], aw1 = attn_w[1], aw2 = attn_w[2];
    const float iws = fast_rcp(aw0 + aw1 + aw2);
    const f32x4* p = (const f32x4*)po;
    const int NQ = BB*SS;

    f32x4 s01 = p[(size_t)0*65536 + v] + p[(size_t)1*65536 + v];
    f32x4 s23 = p[(size_t)2*65536 + v] + p[(size_t)3*65536 + v];
    f32x4 s3s = {0,0,0,0};
    float l3 = 0.f;
    for (int s = 0; s < ns; ++s) {
        s3s += p[(size_t)(4+s)*65536 + v];
        l3 += lb[(4+s)*NQ + qg];
    }
    const float f0 = aw0 * iws * fast_rcp(lb[0*NQ + qg] + lb[1*NQ + qg]);
    const float f1 = aw1 * iws * fast_rcp(lb[2*NQ + qg] + lb[3*NQ + qg]);
    const float f2 = aw2 * iws * fast_rcp(l3);
    f32x4 o;
    #pragma unroll
    for (int u = 0; u < 4; ++u)
        o[u] = __builtin_fmaf(s01[u], f0,
               __builtin_fmaf(s23[u], f1, s3s[u]*f2));
    ((f32x4*)out)[v] = o;
}

extern "C" void kernel_launch(void* const* d_in, const int* in_sizes, int n_in,
                              void* d_out, int out_size, void* d_ws, size_t ws_size,
                              hipStream_t stream) {
    (void)in_sizes; (void)n_in; (void)out_size; (void)ws_size;
    const float* x          = (const float*)d_in[0];
    const float* Wq         = (const float*)d_in[1];
    const float* Wk         = (const float*)d_in[2];
    const float* bk         = (const float*)d_in[3];
    const float* Wv         = (const float*)d_in[4];
    const float* attn_w     = (const float*)d_in[5];
    const float* attn_scale = (const float*)d_in[6];
    float* out              = (float*)d_out;

    // workspace carve-up (~45 MB; ws is ~268 MB)
    float* exf = (float*)d_ws;                            // [B,S,64] f32
    unsigned short* qh  = (unsigned short*)(exf + NSD);   // 6 bf16 [B,S,64]
    unsigned short* ql  = qh  + NSD;
    unsigned short* kh  = ql  + NSD;
    unsigned short* kl  = kh  + NSD;
    unsigned short* xh  = kl  + NSD;
    unsigned short* xlo = xh  + NSD;
    unsigned short* xT  = xlo + NSD;                      // bf16 [B,64,S]
    unsigned short* vT  = xT  + NSD;
    float* po = (float*)(vT + NSD);                       // [36][B,S,64] f32
    float* lb = po + (size_t)36*NSD;                      // [36][B*S]

    k_proj <<<1024, 256, 0, stream>>>(x, Wq, Wk, bk, Wv,
                                      qh, ql, kh, kl, xh, xlo, exf, xT, vT);
    k_fused<<<1296, 256, 0, stream>>>(xh, xlo, qh, ql, kh, kl, exf, xT, vT,
                                      attn_scale, po, lb);
    k_comb <<<256, 256, 0, stream>>>(po, lb, attn_w, out);
}